// Round 4
// baseline (141.799 us; speedup 1.0000x reference)
//
#include <hip/hip_runtime.h>
#include <math.h>

#define BATCH 2048
#define NW    16384   // neurons = 128*128
#define FEAT  256
#define SOMC  128
#define BM    128
#define BN    128
#define KTILES 8      // 8 K-tiles of 64 bf16 (32 hi | 32 lo)
#define SPLITK 512    // bf16 per row after hi/lo split

typedef __attribute__((ext_vector_type(8)))  short short8v;   // 8 bf16 = 4 VGPR
typedef __attribute__((ext_vector_type(16))) float f32x16;    // 32x32 MFMA acc

// ---- ws layout ----
// xn   : 0                      2048 f32
// wn   : 8192                   16384 f32
// bmu  : 73728                  2048 u64
// xsp  : 90112                  2048*512 bf16 (2 MB)
// wsp  : 2187264                16384*512 bf16 (16 MB)
#define WS_NEEDED 18964480ull

static __device__ __forceinline__ unsigned short f2bf(float f) {
    unsigned u = __float_as_uint(f);
    unsigned r = u + 0x7FFFu + ((u >> 16) & 1u);  // RNE
    return (unsigned short)(r >> 16);
}

static __device__ __forceinline__ void gload16(const void* g, void* l) {
    __builtin_amdgcn_global_load_lds(
        (const __attribute__((address_space(1))) unsigned int*)g,
        (__attribute__((address_space(3))) unsigned int*)l, 16, 0, 0);
}

// ---------------- prep: norms + bmu init + hi/lo bf16 split ----------------
__global__ __launch_bounds__(256) void som_prep_split(const float* __restrict__ x,
                                                      const float* __restrict__ w,
                                                      float* __restrict__ xn,
                                                      float* __restrict__ wn,
                                                      unsigned long long* __restrict__ bmu,
                                                      unsigned short* __restrict__ xsp,
                                                      unsigned short* __restrict__ wsp) {
    const int wv = threadIdx.x >> 6;
    const int lane = threadIdx.x & 63;
    const int row = blockIdx.x * 4 + wv;            // 0 .. 18431
    const bool isx = row < BATCH;
    const float* src = isx ? x + (size_t)row * FEAT
                           : w + (size_t)(row - BATCH) * FEAT;
    float4 v = ((const float4*)src)[lane];          // k = lane*4 .. +3
    float s = v.x * v.x + v.y * v.y + v.z * v.z + v.w * v.w;
    #pragma unroll
    for (int o = 32; o; o >>= 1) s += __shfl_xor(s, o, 64);

    float fx[4] = {v.x, v.y, v.z, v.w};
    unsigned short h[4], l[4];
    #pragma unroll
    for (int i = 0; i < 4; ++i) {
        h[i] = f2bf(fx[i]);
        float hf = __uint_as_float((unsigned)h[i] << 16);
        l[i] = f2bf(fx[i] - hf);
    }
    unsigned short* dst = isx ? xsp + (size_t)row * SPLITK
                              : wsp + (size_t)(row - BATCH) * SPLITK;
    const int k = lane * 4;
    const int base = (k >> 5) * 64 + (k & 31);      // K-tile slot: [32 hi | 32 lo]
    *(ushort4*)(dst + base)      = make_ushort4(h[0], h[1], h[2], h[3]);
    *(ushort4*)(dst + base + 32) = make_ushort4(l[0], l[1], l[2], l[3]);

    if (lane == 0) {
        if (isx) { xn[row] = s; bmu[row] = 0xFFFFFFFFFFFFFFFFULL; }
        else     { wn[row - BATCH] = s; }
    }
}

// ---------------- main MFMA kernel: 32x32x16, 3-pass hi/lo ----------------
__global__ __launch_bounds__(256, 4) void som_mfma(const unsigned short* __restrict__ xsp,
                                                   const unsigned short* __restrict__ wsp,
                                                   const float* __restrict__ xn,
                                                   const float* __restrict__ wn,
                                                   float* __restrict__ out,
                                                   unsigned long long* __restrict__ bmu) {
    // LDS tiles: 128 rows x 128 B (one K-tile: 32 hi + 32 lo bf16 per row).
    // Written LINEARLY by global_load_lds; XOR swizzle lives in the
    // pre-swizzled global source chunk (source-perm == read-perm, rule #21).
    __shared__ __align__(16) char xsb[128 * 128];
    __shared__ __align__(16) char wsb[128 * 128];

    const int t = threadIdx.x;
    const int brow = blockIdx.y * BM;
    const int bcol = blockIdx.x * BN;
    const int lane = t & 63, wv = t >> 6;
    const int wrow = (wv >> 1) * 64;   // wave tile origin (64x64 per wave)
    const int wcol = (wv & 1) * 64;
    const int c32 = lane & 31, q5 = lane >> 5;

    // staging: wave owns rows [wv*32, wv*32+32) of both tiles
    const int srow   = wv * 32 + (lane >> 3);
    const int schunk = (lane & 7) ^ (lane >> 3);
    const unsigned short* gx = xsp + (size_t)(brow + srow) * SPLITK + schunk * 8;
    const unsigned short* gw = wsp + (size_t)(bcol + srow) * SPLITK + schunk * 8;
    char* lx = xsb + (wv * 32) * 128;
    char* lw = wsb + (wv * 32) * 128;

    f32x16 zz;
    #pragma unroll
    for (int i = 0; i < 16; ++i) zz[i] = 0.0f;
    f32x16 acc00 = zz, acc01 = zz, acc10 = zz, acc11 = zz;   // [m][n] 32x32 tiles

    #pragma unroll
    for (int kt = 0; kt < KTILES; ++kt) {
        #pragma unroll
        for (int j = 0; j < 4; ++j) {
            gload16(gx + (size_t)j * 8 * SPLITK + kt * 64, lx + j * 1024);
            gload16(gw + (size_t)j * 8 * SPLITK + kt * 64, lw + j * 1024);
        }
        __syncthreads();   // drains vmcnt -> tile ready

        #pragma unroll
        for (int ks = 0; ks < 2; ++ks) {
            // frag = 16 B at row (base + lane&31), global chunk (region + q5*16)
            const int hiB = ks * 32 + q5 * 16;        // hi: bytes [0,64)
            const int loB = 64 + ks * 32 + q5 * 16;   // lo: bytes [64,128)
            #define LDF(buf, r, gc) (*(const short8v*)((buf) + (r) * 128 + ((gc) ^ (((r) & 7) << 4))))
            const int ra0 = wrow + c32, ra1 = wrow + 32 + c32;
            const int rb0 = wcol + c32, rb1 = wcol + 32 + c32;
            short8v ah0 = LDF(xsb, ra0, hiB), ah1 = LDF(xsb, ra1, hiB);
            short8v al0 = LDF(xsb, ra0, loB), al1 = LDF(xsb, ra1, loB);
            short8v bh0 = LDF(wsb, rb0, hiB), bh1 = LDF(wsb, rb1, hiB);
            short8v bl0 = LDF(wsb, rb0, loB), bl1 = LDF(wsb, rb1, loB);
            #undef LDF
            // hh
            acc00 = __builtin_amdgcn_mfma_f32_32x32x16_bf16(ah0, bh0, acc00, 0, 0, 0);
            acc01 = __builtin_amdgcn_mfma_f32_32x32x16_bf16(ah0, bh1, acc01, 0, 0, 0);
            acc10 = __builtin_amdgcn_mfma_f32_32x32x16_bf16(ah1, bh0, acc10, 0, 0, 0);
            acc11 = __builtin_amdgcn_mfma_f32_32x32x16_bf16(ah1, bh1, acc11, 0, 0, 0);
            // hl
            acc00 = __builtin_amdgcn_mfma_f32_32x32x16_bf16(ah0, bl0, acc00, 0, 0, 0);
            acc01 = __builtin_amdgcn_mfma_f32_32x32x16_bf16(ah0, bl1, acc01, 0, 0, 0);
            acc10 = __builtin_amdgcn_mfma_f32_32x32x16_bf16(ah1, bl0, acc10, 0, 0, 0);
            acc11 = __builtin_amdgcn_mfma_f32_32x32x16_bf16(ah1, bl1, acc11, 0, 0, 0);
            // lh  (ll term ~2^-18 relative: dropped)
            acc00 = __builtin_amdgcn_mfma_f32_32x32x16_bf16(al0, bh0, acc00, 0, 0, 0);
            acc01 = __builtin_amdgcn_mfma_f32_32x32x16_bf16(al0, bh1, acc01, 0, 0, 0);
            acc10 = __builtin_amdgcn_mfma_f32_32x32x16_bf16(al1, bh0, acc10, 0, 0, 0);
            acc11 = __builtin_amdgcn_mfma_f32_32x32x16_bf16(al1, bh1, acc11, 0, 0, 0);
        }
        __syncthreads();   // all ds_reads done before next tile overwrites LDS
    }

    // ---- epilogue: full-line stores + argmin ----
    // 32x32 C/D mapping (m74/m101): col = lane&31, row = (reg&3)+8*(reg>>2)+4*(lane>>5)
    #pragma unroll
    for (int m = 0; m < 2; ++m) {
        const f32x16 a0 = m ? acc10 : acc00;
        const f32x16 a1 = m ? acc11 : acc01;
        #pragma unroll
        for (int reg = 0; reg < 16; ++reg) {
            const int rg = brow + wrow + m * 32 + (reg & 3) + 8 * (reg >> 2) + 4 * q5;
            const float xv = xn[rg];
            unsigned long long best = 0xFFFFFFFFFFFFFFFFULL;
            #pragma unroll
            for (int n = 0; n < 2; ++n) {
                const int cg = bcol + wcol + n * 32 + c32;
                const float dot = n ? a1[reg] : a0[reg];
                float d2 = fmaxf(xv + wn[cg] - 2.0f * dot, 0.0f);
                float d = sqrtf(d2);
                out[(size_t)rg * NW + cg] = d;   // 32 lanes x 4 B = full 128-B line
                unsigned long long p =
                    ((unsigned long long)__float_as_uint(d) << 32) | (unsigned)cg;
                if (p < best) best = p;
            }
            #pragma unroll
            for (int o = 16; o; o >>= 1) {       // stays within 32-lane half
                unsigned long long ob = __shfl_xor(best, o, 64);
                if (ob < best) best = ob;
            }
            if (c32 == 0) atomicMin(&bmu[rg], best);
        }
    }
}

// ---------------- fallback f32 path (round-1, known-passing) ----------------
#define BK  32
#define LDK 36

__global__ __launch_bounds__(256) void som_prep(const float* __restrict__ x,
                                                const float* __restrict__ w,
                                                float* __restrict__ xn,
                                                float* __restrict__ wn,
                                                unsigned long long* __restrict__ bmu) {
    const int wave = threadIdx.x >> 6;
    const int lane = threadIdx.x & 63;
    const int row  = blockIdx.x * 4 + wave;
    const float* src = (row < BATCH) ? (x + (size_t)row * FEAT)
                                     : (w + (size_t)(row - BATCH) * FEAT);
    float4 v = ((const float4*)src)[lane];
    float s = v.x * v.x + v.y * v.y + v.z * v.z + v.w * v.w;
    #pragma unroll
    for (int off = 32; off >= 1; off >>= 1) s += __shfl_xor(s, off, 64);
    if (lane == 0) {
        if (row < BATCH) { xn[row] = s; bmu[row] = 0xFFFFFFFFFFFFFFFFULL; }
        else             { wn[row - BATCH] = s; }
    }
}

__global__ __launch_bounds__(256) void som_f32main(const float* __restrict__ x,
                                                   const float* __restrict__ w,
                                                   const float* __restrict__ xn,
                                                   const float* __restrict__ wn,
                                                   float* __restrict__ out,
                                                   unsigned long long* __restrict__ bmu) {
    __shared__ float xs[BM][LDK];
    __shared__ float wsh[BN][LDK];
    const int t  = threadIdx.x;
    const int tx = t & 15;
    const int ty = t >> 4;
    const int brow = blockIdx.y * BM;
    const int bcol = blockIdx.x * BN;
    float acc[8][8];
    #pragma unroll
    for (int i = 0; i < 8; ++i)
        #pragma unroll
        for (int j = 0; j < 8; ++j) acc[i][j] = 0.0f;
    for (int k0 = 0; k0 < FEAT; k0 += BK) {
        #pragma unroll
        for (int r = 0; r < 4; ++r) {
            const int flat = (t + r * 256) * 4;
            const int row  = flat >> 5;
            const int col  = flat & 31;
            float4 xv = *(const float4*)&x[(size_t)(brow + row) * FEAT + k0 + col];
            float4 wv = *(const float4*)&w[(size_t)(bcol + row) * FEAT + k0 + col];
            *(float4*)&xs[row][col]  = xv;
            *(float4*)&wsh[row][col] = wv;
        }
        __syncthreads();
        #pragma unroll
        for (int kq = 0; kq < BK / 4; ++kq) {
            float4 a[8], b[8];
            #pragma unroll
            for (int i = 0; i < 8; ++i) a[i] = *(const float4*)&xs[ty + 16 * i][kq * 4];
            #pragma unroll
            for (int j = 0; j < 8; ++j) b[j] = *(const float4*)&wsh[tx + 16 * j][kq * 4];
            #pragma unroll
            for (int i = 0; i < 8; ++i)
                #pragma unroll
                for (int j = 0; j < 8; ++j) {
                    acc[i][j] += a[i].x * b[j].x;
                    acc[i][j] += a[i].y * b[j].y;
                    acc[i][j] += a[i].z * b[j].z;
                    acc[i][j] += a[i].w * b[j].w;
                }
        }
        __syncthreads();
    }
    #pragma unroll
    for (int i = 0; i < 8; ++i) {
        const int rg = brow + ty + 16 * i;
        const float xnv = xn[rg];
        unsigned long long best = 0xFFFFFFFFFFFFFFFFULL;
        #pragma unroll
        for (int j = 0; j < 8; ++j) {
            const int cg = bcol + tx + 16 * j;
            float d2 = xnv + wn[cg] - 2.0f * acc[i][j];
            d2 = fmaxf(d2, 0.0f);
            float d = sqrtf(d2);
            out[(size_t)rg * NW + cg] = d;
            unsigned long long p =
                ((unsigned long long)__float_as_uint(d) << 32) | (unsigned int)cg;
            if (p < best) best = p;
        }
        #pragma unroll
        for (int off = 8; off >= 1; off >>= 1) {
            unsigned long long o = __shfl_xor(best, off, 64);
            if (o < best) best = o;
        }
        if (tx == 0) atomicMin(&bmu[rg], best);
    }
}

__global__ __launch_bounds__(256) void som_bmu_write(const unsigned long long* __restrict__ bmu,
                                                     float* __restrict__ outb) {
    const int i = blockIdx.x * blockDim.x + threadIdx.x;
    if (i >= BATCH) return;
    const unsigned int idx = (unsigned int)(bmu[i] & 0xFFFFFFFFu);
    outb[(size_t)i * 2 + 0] = (float)(idx >> 7);
    outb[(size_t)i * 2 + 1] = (float)(idx & (SOMC - 1));
}

extern "C" void kernel_launch(void* const* d_in, const int* in_sizes, int n_in,
                              void* d_out, int out_size, void* d_ws, size_t ws_size,
                              hipStream_t stream) {
    const float* x = (const float*)d_in[0];
    const float* w = (const float*)d_in[1];
    float* out = (float*)d_out;

    float* xn = (float*)d_ws;
    float* wn = xn + BATCH;
    unsigned long long* bmu = (unsigned long long*)((char*)d_ws + 73728);
    float* outb = out + (size_t)BATCH * NW;

    if (ws_size >= WS_NEEDED) {
        unsigned short* xsp = (unsigned short*)((char*)d_ws + 90112);
        unsigned short* wsp = (unsigned short*)((char*)d_ws + 2187264);
        som_prep_split<<<(BATCH + NW) / 4, 256, 0, stream>>>(x, w, xn, wn, bmu, xsp, wsp);
        dim3 grid(NW / BN, BATCH / BM);   // 128 x 16
        som_mfma<<<grid, 256, 0, stream>>>(xsp, wsp, xn, wn, out, bmu);
    } else {
        som_prep<<<(BATCH + NW) / 4, 256, 0, stream>>>(x, w, xn, wn, bmu);
        dim3 grid(NW / BN, BATCH / BM);
        som_f32main<<<grid, 256, 0, stream>>>(x, w, xn, wn, out, bmu);
    }
    som_bmu_write<<<(BATCH + 255) / 256, 256, 0, stream>>>(bmu, outb);
}